// Round 13
// baseline (142.784 us; speedup 1.0000x reference)
//
#include <hip/hip_runtime.h>
#include <stdint.h>

#define WW 48
#define NQ 2304             // 48*48
#define NWT 144             // (bh, qt) tiles of 256 queries
#define NGG 8               // kc-pair groups (block covers 2 kc chunks)
#define SCL 0.51011868f     // 8^-0.5 * log2(e)  (folded so softmax = exp2)
#define SHIFT 17.312340491f // 12 * log2(e)      (fixed-shift softmax)
#define PSLAB 2304          // 9*256 floats per (gg, wt) slab

typedef float v2f __attribute__((ext_vector_type(2)));

__device__ __forceinline__ v2f v2fma(v2f a, v2f b, v2f c) {
    return __builtin_elementwise_fma(a, b, c);   // -> v_pk_fma_f32
}

// ---------------------------------------------------------------------------
// attn: R12 geometry (proven: 92us, no spill, conflicts 0) with the inner
// arithmetic rewritten in packed fp32 (v_pk_fma_f32, VOP3P): QK dot 8->4,
// V-accum 8->4, rel dots 8->4. Per-pair VALU 20 -> 13 instructions — attacks
// the measured invariant (~50us VALU busy across R5/R10/R12 regardless of
// LDS traffic or TLP).
// Block = 4 waves over the SAME 256-query tile: wave wv -> kc_local = wv>>1
// (chunk of 3 key-cols), rowhalf = wv&1. grid 1152 = 16bh*9qt*8gg -> 4608
// waves. __launch_bounds__(256,2): budget 128 VGPR (R10/R12-proven; (256,4)
// made the allocator pick 64 -> 3.8GB scratch, R11).
// Keys via wave-uniform ds_read_b128 LDS broadcast (R5-verified delivery).
// qh batched per 8-row round from global relh (L1-hot).
// logit = q.k + q.rel_w[x2-x+47] + q.rel_h[y2-y+47]; p = exp2(logit'-SHIFT)
// Two-phase in-block merge (LDS reuse) -> P slab per (gg, wt).
// ---------------------------------------------------------------------------
__global__ __launch_bounds__(256, 2) void attn_kernel(const float* __restrict__ in,
                                                      const float* __restrict__ relw,
                                                      const float* __restrict__ relh,
                                                      float* __restrict__ P) {
    __shared__ float4 lds[1152];       // 18432 B: staging, later 2 merge regions

    const int bx = blockIdx.x;
    const int bh = bx / 72;
    const int rem = bx - bh * 72;
    const int qt = rem >> 3;           // 0..8
    const int gg = rem & 7;            // 0..7  -> kc = gg*2 + kc_local
    const int tid = threadIdx.x;
    const int lane = tid & 63;
    const int wv = tid >> 6;           // 0..3
    const int kc_local = wv >> 1;
    const int rowhalf = wv & 1;
    const int kc = gg * 2 + kc_local;  // 0..15 (3 columns each)
    const int b = bh >> 3, h = bh & 7;
    const int wt = bh * 9 + qt;

    // ---- stage the block's 2 chunks: 48 rows x 3 cols x [K|V] each ----
    const float4* inp4 = (const float4*)in;
    for (int t = tid; t < 1152; t += 256) {
        const int chunk = t / 576, tt = t - chunk * 576;
        const int key = tt >> 2, p = tt & 3;
        const int row = key / 3, col = key - row * 3;
        const size_t px = (size_t)(b * NQ + row * 48 + (gg * 2 + chunk) * 3 + col) * 48;
        const int c4 = (p < 2) ? (16 + h * 2 + p) : (32 + h * 2 + (p - 2));
        lds[t] = inp4[px + c4];
    }

    // ---- this lane's four queries (packed fp32 pairs) ----
    v2f Q0[4], Q1[4], Q2[4], Q3[4];    // q pairs (01,23,45,67), pre-scaled
    int yq[4], xq[4];
#pragma unroll
    for (int j = 0; j < 4; ++j) {
        const int n = qt * 256 + j * 64 + lane;
        const int y = n / WW;
        yq[j] = y; xq[j] = n - y * WW;
        const float* qp = in + ((size_t)(b * NQ + n) * 192 + h * 8);
        float4 a = *(const float4*)qp, bb = *(const float4*)(qp + 4);
        Q0[j] = (v2f){a.x * SCL, a.y * SCL};
        Q1[j] = (v2f){a.z * SCL, a.w * SCL};
        Q2[j] = (v2f){bb.x * SCL, bb.y * SCL};
        Q3[j] = (v2f){bb.z * SCL, bb.w * SCL};
    }

    // ---- qw per (query, chunk column) from global relw ----
    float qw[4][3];
#pragma unroll
    for (int j = 0; j < 4; ++j)
#pragma unroll
        for (int c = 0; c < 3; ++c) {
            const float* rw = relw + (kc * 3 + c - xq[j] + 47) * 8;
            float4 ta = *(const float4*)rw, tb = *(const float4*)(rw + 4);
            v2f s = v2fma(Q0[j], (v2f){ta.x, ta.y},
                    v2fma(Q1[j], (v2f){ta.z, ta.w},
                    v2fma(Q2[j], (v2f){tb.x, tb.y},
                          Q3[j] * (v2f){tb.z, tb.w})));
            qw[j][c] = s.x + s.y;
        }

    __syncthreads();   // staged KV visible to the 2 waves sharing each chunk

    float l[4] = {0, 0, 0, 0};
    v2f A0[4], A1[4], A2[4], A3[4];    // V-accumulator pairs per query
#pragma unroll
    for (int j = 0; j < 4; ++j) {
        A0[j] = (v2f){0.f, 0.f}; A1[j] = (v2f){0.f, 0.f};
        A2[j] = (v2f){0.f, 0.f}; A3[j] = (v2f){0.f, 0.f};
    }
    const float* myl = (const float*)(lds + kc_local * 576);

#pragma unroll 1
    for (int R = 0; R < 3; ++R) {
        // ---- batch qh for this round's 8 rows (global relh, L1-hot) ----
        float qh[4][8];
#pragma unroll
        for (int row = 0; row < 8; ++row) {
            const int y2 = rowhalf * 24 + R * 8 + row;
#pragma unroll
            for (int j = 0; j < 4; ++j) {
                const float* rh = relh + (y2 - yq[j] + 47) * 8;
                float4 ta = *(const float4*)rh, tb = *(const float4*)(rh + 4);
                v2f s = v2fma(Q0[j], (v2f){ta.x, ta.y},
                        v2fma(Q1[j], (v2f){ta.z, ta.w},
                        v2fma(Q2[j], (v2f){tb.x, tb.y},
                              Q3[j] * (v2f){tb.z, tb.w})));
                qh[j][row] = s.x + s.y - SHIFT;
            }
        }

#pragma unroll 2
        for (int row = 0; row < 8; ++row) {
            const int y2 = rowhalf * 24 + R * 8 + row;
#pragma unroll
            for (int c = 0; c < 3; ++c) {
                const int base = (y2 * 3 + c) * 16;     // wave-uniform
                const float4 k0 = *(const float4*)(myl + base);
                const float4 k1 = *(const float4*)(myl + base + 4);
                const float4 v0 = *(const float4*)(myl + base + 8);
                const float4 v1 = *(const float4*)(myl + base + 12);
                const v2f K0 = {k0.x, k0.y}, K1 = {k0.z, k0.w};
                const v2f K2 = {k1.x, k1.y}, K3 = {k1.z, k1.w};
                const v2f V0 = {v0.x, v0.y}, V1 = {v0.z, v0.w};
                const v2f V2 = {v1.x, v1.y}, V3 = {v1.z, v1.w};
#pragma unroll
                for (int j = 0; j < 4; ++j) {
                    v2f d = v2fma(Q0[j], K0,
                            v2fma(Q1[j], K1,
                            v2fma(Q2[j], K2, Q3[j] * K3)));
                    const float p = __builtin_amdgcn_exp2f(
                        (qh[j][row] + qw[j][c]) + (d.x + d.y));
                    l[j] += p;
                    const v2f pp = {p, p};
                    A0[j] = v2fma(pp, V0, A0[j]);
                    A1[j] = v2fma(pp, V1, A1[j]);
                    A2[j] = v2fma(pp, V2, A2[j]);
                    A3[j] = v2fma(pp, V3, A3[j]);
                }
            }
        }
    }

    // ---- two-phase in-block merge (reuse staging LDS: 2 regions) ----
    __syncthreads();   // everyone done reading staged KV
    float* mr = (float*)(lds + kc_local * 576);   // region per wave-pair
    if (rowhalf == 0) {
#pragma unroll
        for (int j = 0; j < 4; ++j) {
            const int q = j * 64 + lane;
            mr[q] = l[j];
            mr[1 * 256 + q] = A0[j].x; mr[2 * 256 + q] = A0[j].y;
            mr[3 * 256 + q] = A1[j].x; mr[4 * 256 + q] = A1[j].y;
            mr[5 * 256 + q] = A2[j].x; mr[6 * 256 + q] = A2[j].y;
            mr[7 * 256 + q] = A3[j].x; mr[8 * 256 + q] = A3[j].y;
        }
    }
    __syncthreads();
    if (rowhalf == 1) {
#pragma unroll
        for (int j = 0; j < 4; ++j) {
            const int q = j * 64 + lane;
            mr[q] += l[j];
            mr[1 * 256 + q] += A0[j].x; mr[2 * 256 + q] += A0[j].y;
            mr[3 * 256 + q] += A1[j].x; mr[4 * 256 + q] += A1[j].y;
            mr[5 * 256 + q] += A2[j].x; mr[6 * 256 + q] += A2[j].y;
            mr[7 * 256 + q] += A3[j].x; mr[8 * 256 + q] += A3[j].y;
        }
    }
    __syncthreads();

    const float* r0 = (const float*)lds;
    const float* r1 = (const float*)(lds + 576);
    float* pb = P + (size_t)(gg * NWT + wt) * PSLAB;
    for (int idx = tid; idx < PSLAB; idx += 256)
        pb[idx] = r0[idx] + r1[idx];
}

// ---------------------------------------------------------------------------
// merge: sum 8 group-partials per query, normalize, write out[b][n][h*8+j]
// ---------------------------------------------------------------------------
__global__ __launch_bounds__(256) void merge_kernel(const float* __restrict__ P,
                                                    float* __restrict__ out) {
    const int t = blockIdx.x * 256 + threadIdx.x;   // [0, 36864)
    const int wt = t >> 8, q = t & 255;
    float s[9];
#pragma unroll
    for (int j = 0; j < 9; ++j) s[j] = 0.0f;
#pragma unroll
    for (int g = 0; g < NGG; ++g) {
        const float* pb = P + (size_t)(g * NWT + wt) * PSLAB;
#pragma unroll
        for (int j = 0; j < 9; ++j) s[j] += pb[j * 256 + q];
    }
    const float inv = 1.0f / s[0];
    const int bh = wt / 9;
    const int qtl = wt - bh * 9;
    const int n = qtl * 256 + q;
    const int b = bh >> 3, h = bh & 7;
    float* op = out + ((size_t)(b * NQ + n) * 64 + h * 8);
    ((float4*)op)[0] = make_float4(s[1]*inv, s[2]*inv, s[3]*inv, s[4]*inv);
    ((float4*)op)[1] = make_float4(s[5]*inv, s[6]*inv, s[7]*inv, s[8]*inv);
}

extern "C" void kernel_launch(void* const* d_in, const int* in_sizes, int n_in,
                              void* d_out, int out_size, void* d_ws, size_t ws_size,
                              hipStream_t stream) {
    const float* in   = (const float*)d_in[0];
    const float* relw = (const float*)d_in[1];
    const float* relh = (const float*)d_in[2];
    float* P   = (float*)d_ws;    // 8 * 144 * 2304 * 4 B = 10.6 MB (proven fit)
    float* out = (float*)d_out;

    attn_kernel<<<16 * 9 * 8, 256, 0, stream>>>(in, relw, relh, P);
    merge_kernel<<<144, 256, 0, stream>>>(P, out);
}

// Round 14
// 137.606 us; speedup vs baseline: 1.0376x; 1.0376x over previous
//
#include <hip/hip_runtime.h>
#include <stdint.h>

#define WW 48
#define NQ 2304             // 48*48
#define NWT 144             // (bh, qt) tiles of 256 queries
#define SCL 0.51011868f     // 8^-0.5 * log2(e)  (folded so softmax = exp2)
#define SHIFT 17.312340491f // 12 * log2(e)      (fixed-shift softmax)
#define ACCF (NWT * 2304)   // 331776 floats: ACC[wt][9][256]
// ws layout (floats): [0, ACCF) ACC | [ACCF, ACCF + 16*48*2304) QH

typedef float v2f __attribute__((ext_vector_type(2)));

__device__ __forceinline__ v2f v2fma(v2f a, v2f b, v2f c) {
    return __builtin_elementwise_fma(a, b, c);   // -> v_pk_fma_f32
}

// ---------------------------------------------------------------------------
// qh_pre: QH[bh][y2][n] = (q_n*SCL) . relh[y2 - y(n) + 47] - SHIFT
// Coalesced dword writes; kills the 8x-redundant in-loop qh dots AND the
// L1-heaviest load stream of the attn kernel (192 dwordx4/wave -> 96 dword).
// ---------------------------------------------------------------------------
__global__ __launch_bounds__(256) void qh_pre(const float* __restrict__ in,
                                              const float* __restrict__ relh,
                                              float* __restrict__ QH) {
    const int bh = blockIdx.x / 9;
    const int nt = blockIdx.x - bh * 9;
    const int n = nt * 256 + threadIdx.x;
    const int b = bh >> 3, h = bh & 7;
    const int y = n / WW;

    const float* qp = in + ((size_t)(b * NQ + n) * 192 + h * 8);
    float4 a = *(const float4*)qp, bb = *(const float4*)(qp + 4);
    v2f Q0 = {a.x * SCL, a.y * SCL}, Q1 = {a.z * SCL, a.w * SCL};
    v2f Q2 = {bb.x * SCL, bb.y * SCL}, Q3 = {bb.z * SCL, bb.w * SCL};

    for (int y2 = 0; y2 < 48; ++y2) {
        const float* rh = relh + (y2 - y + 47) * 8;
        float4 ta = *(const float4*)rh, tb = *(const float4*)(rh + 4);
        v2f s = v2fma(Q0, (v2f){ta.x, ta.y},
                v2fma(Q1, (v2f){ta.z, ta.w},
                v2fma(Q2, (v2f){tb.x, tb.y},
                      Q3 * (v2f){tb.z, tb.w})));
        QH[(size_t)(bh * 48 + y2) * 2304 + n] = s.x + s.y - SHIFT;
    }
}

// ---------------------------------------------------------------------------
// attn: R13 engine (LDS-broadcast KV, 4 q/lane, packed fp32), with
//  (1) qh loaded from precomputed QH (coalesced dword, L1 pipe 28->10us)
//  (2) partials accumulated via global fp32 atomicAdd into ACC (no P slabs,
//      no merge pass; 32 contributors/address, L2-resident, m20-verified).
// Block = 4 waves over the SAME 256-query tile: wave wv -> kc_local = wv>>1
// (chunk of 3 key-cols), rowhalf = wv&1. grid 1152 = 16bh*9qt*8gg.
// __launch_bounds__(256,2): proven 128-VGPR budget, no spill (R11 lesson).
// logit = q.k + q.rel_w[x2-x+47] + q.rel_h[y2-y+47]; p = exp2(logit'-SHIFT)
// ---------------------------------------------------------------------------
__global__ __launch_bounds__(256, 2) void attn_kernel(const float* __restrict__ in,
                                                      const float* __restrict__ relw,
                                                      const float* __restrict__ QH,
                                                      float* __restrict__ ACC) {
    __shared__ float4 lds[1152];       // 18432 B staging

    const int bx = blockIdx.x;
    const int bh = bx / 72;
    const int rem = bx - bh * 72;
    const int qt = rem >> 3;           // 0..8
    const int gg = rem & 7;            // 0..7  -> kc = gg*2 + kc_local
    const int tid = threadIdx.x;
    const int lane = tid & 63;
    const int wv = tid >> 6;           // 0..3
    const int kc_local = wv >> 1;
    const int rowhalf = wv & 1;
    const int kc = gg * 2 + kc_local;  // 0..15 (3 columns each)
    const int b = bh >> 3, h = bh & 7;
    const int wt = bh * 9 + qt;

    // ---- stage the block's 2 chunks: 48 rows x 3 cols x [K|V] each ----
    const float4* inp4 = (const float4*)in;
    for (int t = tid; t < 1152; t += 256) {
        const int chunk = t / 576, tt = t - chunk * 576;
        const int key = tt >> 2, p = tt & 3;
        const int row = key / 3, col = key - row * 3;
        const size_t px = (size_t)(b * NQ + row * 48 + (gg * 2 + chunk) * 3 + col) * 48;
        const int c4 = (p < 2) ? (16 + h * 2 + p) : (32 + h * 2 + (p - 2));
        lds[t] = inp4[px + c4];
    }

    // ---- this lane's four queries (packed fp32 pairs) ----
    v2f Q0[4], Q1[4], Q2[4], Q3[4];
    int xq[4];
#pragma unroll
    for (int j = 0; j < 4; ++j) {
        const int n = qt * 256 + j * 64 + lane;
        const int y = n / WW;
        xq[j] = n - y * WW;
        const float* qp = in + ((size_t)(b * NQ + n) * 192 + h * 8);
        float4 a = *(const float4*)qp, bb = *(const float4*)(qp + 4);
        Q0[j] = (v2f){a.x * SCL, a.y * SCL};
        Q1[j] = (v2f){a.z * SCL, a.w * SCL};
        Q2[j] = (v2f){bb.x * SCL, bb.y * SCL};
        Q3[j] = (v2f){bb.z * SCL, bb.w * SCL};
    }

    // ---- qw per (query, chunk column) from global relw ----
    float qw[4][3];
#pragma unroll
    for (int j = 0; j < 4; ++j)
#pragma unroll
        for (int c = 0; c < 3; ++c) {
            const float* rw = relw + (kc * 3 + c - xq[j] + 47) * 8;
            float4 ta = *(const float4*)rw, tb = *(const float4*)(rw + 4);
            v2f s = v2fma(Q0[j], (v2f){ta.x, ta.y},
                    v2fma(Q1[j], (v2f){ta.z, ta.w},
                    v2fma(Q2[j], (v2f){tb.x, tb.y},
                          Q3[j] * (v2f){tb.z, tb.w})));
            qw[j][c] = s.x + s.y;
        }

    __syncthreads();   // staged KV visible to the 2 waves sharing each chunk

    float l[4] = {0, 0, 0, 0};
    v2f A0[4], A1[4], A2[4], A3[4];
#pragma unroll
    for (int j = 0; j < 4; ++j) {
        A0[j] = (v2f){0.f, 0.f}; A1[j] = (v2f){0.f, 0.f};
        A2[j] = (v2f){0.f, 0.f}; A3[j] = (v2f){0.f, 0.f};
    }
    const float* myl = (const float*)(lds + kc_local * 576);
    const float* qhbase = QH + (size_t)bh * 48 * 2304 + qt * 256 + lane;

#pragma unroll 1
    for (int R = 0; R < 3; ++R) {
        // ---- qh for this round's 8 rows: coalesced dword loads ----
        float qh[4][8];
#pragma unroll
        for (int row = 0; row < 8; ++row) {
            const int y2 = rowhalf * 24 + R * 8 + row;
            const float* qr = qhbase + (size_t)y2 * 2304;
#pragma unroll
            for (int j = 0; j < 4; ++j) qh[j][row] = qr[j * 64];
        }

#pragma unroll 2
        for (int row = 0; row < 8; ++row) {
            const int y2 = rowhalf * 24 + R * 8 + row;
#pragma unroll
            for (int c = 0; c < 3; ++c) {
                const int base = (y2 * 3 + c) * 16;     // wave-uniform
                const float4 k0 = *(const float4*)(myl + base);
                const float4 k1 = *(const float4*)(myl + base + 4);
                const float4 v0 = *(const float4*)(myl + base + 8);
                const float4 v1 = *(const float4*)(myl + base + 12);
                const v2f K0 = {k0.x, k0.y}, K1 = {k0.z, k0.w};
                const v2f K2 = {k1.x, k1.y}, K3 = {k1.z, k1.w};
                const v2f V0 = {v0.x, v0.y}, V1 = {v0.z, v0.w};
                const v2f V2 = {v1.x, v1.y}, V3 = {v1.z, v1.w};
#pragma unroll
                for (int j = 0; j < 4; ++j) {
                    v2f d = v2fma(Q0[j], K0,
                            v2fma(Q1[j], K1,
                            v2fma(Q2[j], K2, Q3[j] * K3)));
                    const float p = __builtin_amdgcn_exp2f(
                        (qh[j][row] + qw[j][c]) + (d.x + d.y));
                    l[j] += p;
                    const v2f pp = {p, p};
                    A0[j] = v2fma(pp, V0, A0[j]);
                    A1[j] = v2fma(pp, V1, A1[j]);
                    A2[j] = v2fma(pp, V2, A2[j]);
                    A3[j] = v2fma(pp, V3, A3[j]);
                }
            }
        }
    }

    // ---- accumulate partials via fp32 atomics: ACC[wt][slot][q] ----
    float* ab = ACC + (size_t)wt * 2304;
#pragma unroll
    for (int j = 0; j < 4; ++j) {
        const int q = j * 64 + lane;
        atomicAdd(ab + q, l[j]);
        atomicAdd(ab + 1 * 256 + q, A0[j].x);
        atomicAdd(ab + 2 * 256 + q, A0[j].y);
        atomicAdd(ab + 3 * 256 + q, A1[j].x);
        atomicAdd(ab + 4 * 256 + q, A1[j].y);
        atomicAdd(ab + 5 * 256 + q, A2[j].x);
        atomicAdd(ab + 6 * 256 + q, A2[j].y);
        atomicAdd(ab + 7 * 256 + q, A3[j].x);
        atomicAdd(ab + 8 * 256 + q, A3[j].y);
    }
}

// ---------------------------------------------------------------------------
// normalize: read ACC, divide by l, write out[b][n][h*8+j]
// ---------------------------------------------------------------------------
__global__ __launch_bounds__(256) void norm_kernel(const float* __restrict__ ACC,
                                                   float* __restrict__ out) {
    const int t = blockIdx.x * 256 + threadIdx.x;   // [0, 36864)
    const int wt = t >> 8, q = t & 255;
    const float* ab = ACC + (size_t)wt * 2304;
    const float inv = 1.0f / ab[q];
    float s[8];
#pragma unroll
    for (int e = 0; e < 8; ++e) s[e] = ab[(1 + e) * 256 + q] * inv;
    const int bh = wt / 9;
    const int qtl = wt - bh * 9;
    const int n = qtl * 256 + q;
    const int b = bh >> 3, h = bh & 7;
    float* op = out + ((size_t)(b * NQ + n) * 64 + h * 8);
    ((float4*)op)[0] = make_float4(s[0], s[1], s[2], s[3]);
    ((float4*)op)[1] = make_float4(s[4], s[5], s[6], s[7]);
}

extern "C" void kernel_launch(void* const* d_in, const int* in_sizes, int n_in,
                              void* d_out, int out_size, void* d_ws, size_t ws_size,
                              hipStream_t stream) {
    const float* in   = (const float*)d_in[0];
    const float* relw = (const float*)d_in[1];
    const float* relh = (const float*)d_in[2];
    float* ACC = (float*)d_ws;                 // 1.33 MB
    float* QH  = (float*)d_ws + ACCF;          // 7.08 MB  (total 8.4 < 10.6 proven)
    float* out = (float*)d_out;

    hipMemsetAsync(ACC, 0, ACCF * sizeof(float), stream);
    qh_pre<<<144, 256, 0, stream>>>(in, relh, QH);
    attn_kernel<<<16 * 9 * 8, 256, 0, stream>>>(in, relw, QH, ACC);
    norm_kernel<<<144, 256, 0, stream>>>(ACC, out);
}

// Round 15
// 127.863 us; speedup vs baseline: 1.1167x; 1.0762x over previous
//
#include <hip/hip_runtime.h>
#include <stdint.h>

#define WW 48
#define NQ 2304             // 48*48
#define NWT 144             // (bh, qt) tiles of 256 queries
#define SCL 0.51011868f     // 8^-0.5 * log2(e)  (folded so softmax = exp2)
#define SHIFT 17.312340491f // 12 * log2(e)      (fixed-shift softmax)
#define ACCF (NWT * 2304)   // 331776 floats: ACC[wt][9][256]
// ws layout (floats): [0, ACCF) ACC | [ACCF, ACCF + 16*48*2304) QH

typedef float v2f __attribute__((ext_vector_type(2)));

__device__ __forceinline__ v2f v2fma(v2f a, v2f b, v2f c) {
    return __builtin_elementwise_fma(a, b, c);   // -> v_pk_fma_f32
}

// ---------------------------------------------------------------------------
// qh_pre: QH[bh][y2][n] = (q_n*SCL) . relh[y2 - y(n) + 47] - SHIFT
// ---------------------------------------------------------------------------
__global__ __launch_bounds__(256) void qh_pre(const float* __restrict__ in,
                                              const float* __restrict__ relh,
                                              float* __restrict__ QH) {
    const int bh = blockIdx.x / 9;
    const int nt = blockIdx.x - bh * 9;
    const int n = nt * 256 + threadIdx.x;
    const int b = bh >> 3, h = bh & 7;
    const int y = n / WW;

    const float* qp = in + ((size_t)(b * NQ + n) * 192 + h * 8);
    float4 a = *(const float4*)qp, bb = *(const float4*)(qp + 4);
    v2f Q0 = {a.x * SCL, a.y * SCL}, Q1 = {a.z * SCL, a.w * SCL};
    v2f Q2 = {bb.x * SCL, bb.y * SCL}, Q3 = {bb.z * SCL, bb.w * SCL};

    for (int y2 = 0; y2 < 48; ++y2) {
        const float* rh = relh + (y2 - y + 47) * 8;
        float4 ta = *(const float4*)rh, tb = *(const float4*)(rh + 4);
        v2f s = v2fma(Q0, (v2f){ta.x, ta.y},
                v2fma(Q1, (v2f){ta.z, ta.w},
                v2fma(Q2, (v2f){tb.x, tb.y},
                      Q3 * (v2f){tb.z, tb.w})));
        QH[(size_t)(bh * 48 + y2) * 2304 + n] = s.x + s.y - SHIFT;
    }
}

// ---------------------------------------------------------------------------
// attn: R14 engine (LDS-broadcast KV, 4 q/lane, packed fp32, precomputed QH)
// with the atomic-coherence fix:
//  (1) XCD-local placement: bx = gg*144 + wt (144 % 8 == 0 -> all 8 gg
//      contributor blocks of a wt share bx%8 -> same XCD under round-robin
//      dispatch). R14's gg = bx%8 spread contributors over all 8 XCDs ->
//      every ACC line ping-ponged cross-XCD -> 76.8 MB TCC-miss traffic at
//      ~1 TB/s == the whole 75.6us kernel dur.
//  (2) Two-phase in-block LDS merge (R12-proven) -> ONE atomic layer per
//      block: 36 wave-atomics instead of 144 (4x less atomic traffic).
// Block = 4 waves over the SAME 256-query tile: wave wv -> kc_local = wv>>1
// (chunk of 3 key-cols), rowhalf = wv&1. __launch_bounds__(256,2): proven
// 128-VGPR budget, no spill (R11 lesson).
// logit = q.k + q.rel_w[x2-x+47] + q.rel_h[y2-y+47]; p = exp2(logit'-SHIFT)
// ---------------------------------------------------------------------------
__global__ __launch_bounds__(256, 2) void attn_kernel(const float* __restrict__ in,
                                                      const float* __restrict__ relw,
                                                      const float* __restrict__ QH,
                                                      float* __restrict__ ACC) {
    __shared__ float4 lds[1152];       // 18432 B: staging, later 2 merge regions

    const int bx = blockIdx.x;
    const int wt = bx % NWT;           // same-wt blocks share bx%8 -> same XCD
    const int gg = bx / NWT;           // 0..7
    const int bh = wt / 9;
    const int qt = wt - bh * 9;
    const int tid = threadIdx.x;
    const int lane = tid & 63;
    const int wv = tid >> 6;           // 0..3
    const int kc_local = wv >> 1;
    const int rowhalf = wv & 1;
    const int kc = gg * 2 + kc_local;  // 0..15 (3 columns each)
    const int b = bh >> 3, h = bh & 7;

    // ---- stage the block's 2 chunks: 48 rows x 3 cols x [K|V] each ----
    const float4* inp4 = (const float4*)in;
    for (int t = tid; t < 1152; t += 256) {
        const int chunk = t / 576, tt = t - chunk * 576;
        const int key = tt >> 2, p = tt & 3;
        const int row = key / 3, col = key - row * 3;
        const size_t px = (size_t)(b * NQ + row * 48 + (gg * 2 + chunk) * 3 + col) * 48;
        const int c4 = (p < 2) ? (16 + h * 2 + p) : (32 + h * 2 + (p - 2));
        lds[t] = inp4[px + c4];
    }

    // ---- this lane's four queries (packed fp32 pairs) ----
    v2f Q0[4], Q1[4], Q2[4], Q3[4];
    int xq[4];
#pragma unroll
    for (int j = 0; j < 4; ++j) {
        const int n = qt * 256 + j * 64 + lane;
        const int y = n / WW;
        xq[j] = n - y * WW;
        const float* qp = in + ((size_t)(b * NQ + n) * 192 + h * 8);
        float4 a = *(const float4*)qp, bb = *(const float4*)(qp + 4);
        Q0[j] = (v2f){a.x * SCL, a.y * SCL};
        Q1[j] = (v2f){a.z * SCL, a.w * SCL};
        Q2[j] = (v2f){bb.x * SCL, bb.y * SCL};
        Q3[j] = (v2f){bb.z * SCL, bb.w * SCL};
    }

    // ---- qw per (query, chunk column) from global relw ----
    float qw[4][3];
#pragma unroll
    for (int j = 0; j < 4; ++j)
#pragma unroll
        for (int c = 0; c < 3; ++c) {
            const float* rw = relw + (kc * 3 + c - xq[j] + 47) * 8;
            float4 ta = *(const float4*)rw, tb = *(const float4*)(rw + 4);
            v2f s = v2fma(Q0[j], (v2f){ta.x, ta.y},
                    v2fma(Q1[j], (v2f){ta.z, ta.w},
                    v2fma(Q2[j], (v2f){tb.x, tb.y},
                          Q3[j] * (v2f){tb.z, tb.w})));
            qw[j][c] = s.x + s.y;
        }

    __syncthreads();   // staged KV visible to the 2 waves sharing each chunk

    float l[4] = {0, 0, 0, 0};
    v2f A0[4], A1[4], A2[4], A3[4];
#pragma unroll
    for (int j = 0; j < 4; ++j) {
        A0[j] = (v2f){0.f, 0.f}; A1[j] = (v2f){0.f, 0.f};
        A2[j] = (v2f){0.f, 0.f}; A3[j] = (v2f){0.f, 0.f};
    }
    const float* myl = (const float*)(lds + kc_local * 576);
    const float* qhbase = QH + (size_t)bh * 48 * 2304 + qt * 256 + lane;

#pragma unroll 1
    for (int R = 0; R < 3; ++R) {
        // ---- qh for this round's 8 rows: coalesced dword loads ----
        float qh[4][8];
#pragma unroll
        for (int row = 0; row < 8; ++row) {
            const int y2 = rowhalf * 24 + R * 8 + row;
            const float* qr = qhbase + (size_t)y2 * 2304;
#pragma unroll
            for (int j = 0; j < 4; ++j) qh[j][row] = qr[j * 64];
        }

#pragma unroll 2
        for (int row = 0; row < 8; ++row) {
            const int y2 = rowhalf * 24 + R * 8 + row;
#pragma unroll
            for (int c = 0; c < 3; ++c) {
                const int base = (y2 * 3 + c) * 16;     // wave-uniform
                const float4 k0 = *(const float4*)(myl + base);
                const float4 k1 = *(const float4*)(myl + base + 4);
                const float4 v0 = *(const float4*)(myl + base + 8);
                const float4 v1 = *(const float4*)(myl + base + 12);
                const v2f K0 = {k0.x, k0.y}, K1 = {k0.z, k0.w};
                const v2f K2 = {k1.x, k1.y}, K3 = {k1.z, k1.w};
                const v2f V0 = {v0.x, v0.y}, V1 = {v0.z, v0.w};
                const v2f V2 = {v1.x, v1.y}, V3 = {v1.z, v1.w};
#pragma unroll
                for (int j = 0; j < 4; ++j) {
                    v2f d = v2fma(Q0[j], K0,
                            v2fma(Q1[j], K1,
                            v2fma(Q2[j], K2, Q3[j] * K3)));
                    const float p = __builtin_amdgcn_exp2f(
                        (qh[j][row] + qw[j][c]) + (d.x + d.y));
                    l[j] += p;
                    const v2f pp = {p, p};
                    A0[j] = v2fma(pp, V0, A0[j]);
                    A1[j] = v2fma(pp, V1, A1[j]);
                    A2[j] = v2fma(pp, V2, A2[j]);
                    A3[j] = v2fma(pp, V3, A3[j]);
                }
            }
        }
    }

    // ---- two-phase in-block merge (reuse staging LDS: 2 regions) ----
    __syncthreads();   // everyone done reading staged KV
    float* mr = (float*)(lds + kc_local * 576);   // region per wave-pair
    if (rowhalf == 0) {
#pragma unroll
        for (int j = 0; j < 4; ++j) {
            const int q = j * 64 + lane;
            mr[q] = l[j];
            mr[1 * 256 + q] = A0[j].x; mr[2 * 256 + q] = A0[j].y;
            mr[3 * 256 + q] = A1[j].x; mr[4 * 256 + q] = A1[j].y;
            mr[5 * 256 + q] = A2[j].x; mr[6 * 256 + q] = A2[j].y;
            mr[7 * 256 + q] = A3[j].x; mr[8 * 256 + q] = A3[j].y;
        }
    }
    __syncthreads();
    if (rowhalf == 1) {
#pragma unroll
        for (int j = 0; j < 4; ++j) {
            const int q = j * 64 + lane;
            mr[q] += l[j];
            mr[1 * 256 + q] += A0[j].x; mr[2 * 256 + q] += A0[j].y;
            mr[3 * 256 + q] += A1[j].x; mr[4 * 256 + q] += A1[j].y;
            mr[5 * 256 + q] += A2[j].x; mr[6 * 256 + q] += A2[j].y;
            mr[7 * 256 + q] += A3[j].x; mr[8 * 256 + q] += A3[j].y;
        }
    }
    __syncthreads();

    // ---- single atomic layer per block (XCD-local ACC lines) ----
    const float* r0 = (const float*)lds;
    const float* r1 = (const float*)(lds + 576);
    float* ab = ACC + (size_t)wt * 2304;
    for (int idx = tid; idx < 2304; idx += 256)
        atomicAdd(ab + idx, r0[idx] + r1[idx]);
}

// ---------------------------------------------------------------------------
// normalize: read ACC, divide by l, write out[b][n][h*8+j]
// ---------------------------------------------------------------------------
__global__ __launch_bounds__(256) void norm_kernel(const float* __restrict__ ACC,
                                                   float* __restrict__ out) {
    const int t = blockIdx.x * 256 + threadIdx.x;   // [0, 36864)
    const int wt = t >> 8, q = t & 255;
    const float* ab = ACC + (size_t)wt * 2304;
    const float inv = 1.0f / ab[q];
    float s[8];
#pragma unroll
    for (int e = 0; e < 8; ++e) s[e] = ab[(1 + e) * 256 + q] * inv;
    const int bh = wt / 9;
    const int qtl = wt - bh * 9;
    const int n = qtl * 256 + q;
    const int b = bh >> 3, h = bh & 7;
    float* op = out + ((size_t)(b * NQ + n) * 64 + h * 8);
    ((float4*)op)[0] = make_float4(s[0], s[1], s[2], s[3]);
    ((float4*)op)[1] = make_float4(s[4], s[5], s[6], s[7]);
}

extern "C" void kernel_launch(void* const* d_in, const int* in_sizes, int n_in,
                              void* d_out, int out_size, void* d_ws, size_t ws_size,
                              hipStream_t stream) {
    const float* in   = (const float*)d_in[0];
    const float* relw = (const float*)d_in[1];
    const float* relh = (const float*)d_in[2];
    float* ACC = (float*)d_ws;                 // 1.33 MB
    float* QH  = (float*)d_ws + ACCF;          // 7.08 MB  (total 8.4 < 10.6 proven)
    float* out = (float*)d_out;

    hipMemsetAsync(ACC, 0, ACCF * sizeof(float), stream);
    qh_pre<<<144, 256, 0, stream>>>(in, relh, QH);
    attn_kernel<<<8 * NWT, 256, 0, stream>>>(in, relw, QH, ACC);
    norm_kernel<<<144, 256, 0, stream>>>(ACC, out);
}